// Round 3
// baseline (165.440 us; speedup 1.0000x reference)
//
#include <hip/hip_runtime.h>
#include <math.h>

#define N_NODES 1024
#define F_DIM   128
#define M_DIM   256
#define E_DIM   8
#define P_PAIRS 523776   // N*(N-1)/2

// ---------- Kernel A: pa/pb projections + stress; block 256 does BN-fold/cterm/b2f ----------
__global__ __launch_bounds__(256) void kA(const float* __restrict__ x,
                                          const float* __restrict__ ctx,
                                          const float* __restrict__ W1,
                                          const float* __restrict__ b1,
                                          const float* __restrict__ gamma,
                                          const float* __restrict__ beta,
                                          const float* __restrict__ rmean,
                                          const float* __restrict__ rvar,
                                          const float* __restrict__ W2,
                                          const float* __restrict__ b2,
                                          float* __restrict__ pa,
                                          float* __restrict__ pb,
                                          float* __restrict__ stress,
                                          float* __restrict__ cterm,
                                          float* __restrict__ w2ft,
                                          float* __restrict__ b2f) {
  const int t = threadIdx.x;

  if (blockIdx.x == 256) {
    // ---- BN fold, cterm, b2f (same arithmetic order as round 2) ----
    __shared__ float bnbs[256];
    const float c0 = ctx[0], c1 = ctx[1], c2 = ctx[2], c3 = ctx[3];
    const float* row = W1 + (size_t)t * 260 + 256;
    cterm[t] = b1[t] + c0 * row[0] + c1 * row[1] + c2 * row[2] + c3 * row[3];
    const float s   = gamma[t] / sqrtf(rvar[t] + 1e-5f);
    bnbs[t] = beta[t] - s * rmean[t];
    #pragma unroll
    for (int e = 0; e < 8; ++e) w2ft[t * 8 + e] = W2[e * 256 + t] * s;
    __syncthreads();
    const int wv = t >> 6, lane = t & 63;
    #pragma unroll
    for (int r = 0; r < 2; ++r) {
      const int e = wv * 2 + r;
      float acc = 0.f;
      #pragma unroll
      for (int k = 0; k < 4; ++k) acc += W2[e * 256 + lane + 64 * k] * bnbs[lane + 64 * k];
      #pragma unroll
      for (int m = 32; m > 0; m >>= 1) acc += __shfl_xor(acc, m, 64);
      if (lane == 0) b2f[e] = acc + b2[e];
    }
    return;
  }

  __shared__ float xv[4][128];
  const int n0 = blockIdx.x * 4;
  if (t < 128) {
    ((float4*)&xv[0][0])[t] = ((const float4*)(x + (size_t)n0 * F_DIM))[t];
  }
  __syncthreads();

  // stress (torch unbiased std over features): one wave per node
  {
    const int wv = t >> 6, lane = t & 63;
    const float a = xv[wv][lane], b = xv[wv][lane + 64];
    float sum = a + b;
    #pragma unroll
    for (int m = 32; m > 0; m >>= 1) sum += __shfl_xor(sum, m, 64);
    const float mean = sum * (1.0f / 128.0f);
    const float d0 = a - mean, d1 = b - mean;
    float ss = d0 * d0 + d1 * d1;
    #pragma unroll
    for (int m = 32; m > 0; m >>= 1) ss += __shfl_xor(ss, m, 64);
    if (lane == 0) stress[n0 + wv] = sqrtf(ss * (1.0f / 127.0f));
  }

  const int m = t;
  const float4* wrow = (const float4*)(W1 + (size_t)m * 260);  // W1 row-major [256][260]
  float accA[4] = {0.f, 0.f, 0.f, 0.f};
  float accB[4] = {0.f, 0.f, 0.f, 0.f};
  #pragma unroll 8
  for (int k4 = 0; k4 < 32; ++k4) {
    const float4 wa = wrow[k4];
    const float4 wb = wrow[32 + k4];
    #pragma unroll
    for (int nn = 0; nn < 4; ++nn) {
      const float4 xf = ((const float4*)&xv[nn][0])[k4];
      accA[nn] = fmaf(xf.w, wa.w, fmaf(xf.z, wa.z, fmaf(xf.y, wa.y, fmaf(xf.x, wa.x, accA[nn]))));
      accB[nn] = fmaf(xf.w, wb.w, fmaf(xf.z, wb.z, fmaf(xf.y, wb.y, fmaf(xf.x, wb.x, accB[nn]))));
    }
  }
  #pragma unroll
  for (int nn = 0; nn < 4; ++nn) {
    pa[(size_t)(n0 + nn) * M_DIM + m] = accA[nn];
    pb[(size_t)(n0 + nn) * M_DIM + m] = accB[nn];
  }
}

// ---------- Kernel C: 16x16 pair tiles, 64-thread single-wave blocks ----------
// LDS: a/b tiles 16 rows x 256 m, float4-col swizzle (c4+row)&63 -> all reads
// are 8-distinct-address/8-lane-broadcast, conflict-free. w2ft read with
// wave-uniform address from global -> scalar loads (s_load), zero LDS traffic.
__global__ __launch_bounds__(64) void kC(const float* __restrict__ pa,
                                         const float* __restrict__ pb,
                                         const float* __restrict__ cterm,
                                         const float* __restrict__ w2ft,
                                         const float* __restrict__ b2f,
                                         const float* __restrict__ W3,
                                         const float* __restrict__ b3,
                                         const float* __restrict__ stress,
                                         float* __restrict__ out) {
  const int ti = blockIdx.x, tj = blockIdx.y;
  if (tj < ti) return;
  __shared__ float aT[16 * 256];
  __shared__ float bT[16 * 256];
  const int t  = threadIdx.x;   // 0..63
  const int i0 = ti * 16, j0 = tj * 16;
  float4* a4 = (float4*)aT;
  float4* b4 = (float4*)bT;

  // ---- stressed-node mean (recomputed per block; ~1% of block time) ----
  float ssum = 0.f;
  #pragma unroll
  for (int k = 0; k < 16; ++k) ssum += stress[t + 64 * k];
  #pragma unroll
  for (int m = 32; m > 0; m >>= 1) ssum += __shfl_xor(ssum, m, 64);
  const float smean = ssum * (1.0f / 1024.0f);

  // ---- stage tiles: q-th iteration loads one full row, perfectly coalesced ----
  const float4 cv = ((const float4*)cterm)[t];
  #pragma unroll
  for (int q = 0; q < 16; ++q) {
    const int sc = (t + q) & 63;                       // swizzled float4-col
    float4 av = ((const float4*)(pa + (size_t)(i0 + q) * M_DIM))[t];
    av.x += cv.x; av.y += cv.y; av.z += cv.z; av.w += cv.w;
    a4[q * 64 + sc] = av;
    b4[q * 64 + sc] = ((const float4*)(pb + (size_t)(j0 + q) * M_DIM))[t];
  }
  __syncthreads();

  const int jx = t & 7;    // j within tile
  const int iy = t >> 3;   // i within tile
  float acc[4][8];         // [pair 00,01,10,11][e]
  #pragma unroll
  for (int p = 0; p < 4; ++p)
    #pragma unroll
    for (int e = 0; e < 8; ++e) acc[p][e] = 0.f;

  const float4* w4 = (const float4*)w2ft;

  #pragma unroll 2
  for (int m4 = 0; m4 < 64; ++m4) {
    const float4 a0 = a4[iy * 64       + ((m4 + iy) & 63)];
    const float4 a1 = a4[(iy + 8) * 64 + ((m4 + iy + 8) & 63)];
    const float4 b0 = b4[jx * 64       + ((m4 + jx) & 63)];
    const float4 b1 = b4[(jx + 8) * 64 + ((m4 + jx + 8) & 63)];
    float4 w[8];
    #pragma unroll
    for (int q = 0; q < 8; ++q) w[q] = w4[m4 * 8 + q];  // uniform -> s_load

    const float* a0f = (const float*)&a0;
    const float* a1f = (const float*)&a1;
    const float* b0f = (const float*)&b0;
    const float* b1f = (const float*)&b1;
    #pragma unroll
    for (int mm = 0; mm < 4; ++mm) {
      const float r00 = fmaxf(a0f[mm] + b0f[mm], 0.f);
      const float r01 = fmaxf(a0f[mm] + b1f[mm], 0.f);
      const float r10 = fmaxf(a1f[mm] + b0f[mm], 0.f);
      const float r11 = fmaxf(a1f[mm] + b1f[mm], 0.f);
      const float* wl = (const float*)&w[mm * 2];      // e 0..3
      const float* wh = (const float*)&w[mm * 2 + 1];  // e 4..7
      #pragma unroll
      for (int e = 0; e < 4; ++e) {
        acc[0][e]     = fmaf(wl[e], r00, acc[0][e]);
        acc[1][e]     = fmaf(wl[e], r01, acc[1][e]);
        acc[2][e]     = fmaf(wl[e], r10, acc[2][e]);
        acc[3][e]     = fmaf(wl[e], r11, acc[3][e]);
        acc[0][e + 4] = fmaf(wh[e], r00, acc[0][e + 4]);
        acc[1][e + 4] = fmaf(wh[e], r01, acc[1][e + 4]);
        acc[2][e + 4] = fmaf(wh[e], r10, acc[2][e + 4]);
        acc[3][e + 4] = fmaf(wh[e], r11, acc[3][e + 4]);
      }
    }
  }

  // ---- epilogue: second relu, W3 dot, sigmoid, mask, triu store ----
  float w3v[8], b2v[8];
  #pragma unroll
  for (int e = 0; e < 8; ++e) { w3v[e] = W3[e]; b2v[e] = b2f[e]; }
  const float b3v = b3[0];
  #pragma unroll
  for (int ia = 0; ia < 2; ++ia) {
    #pragma unroll
    for (int jb = 0; jb < 2; ++jb) {
      const int i = i0 + iy + ia * 8;
      const int j = j0 + jx + jb * 8;
      if (i < j) {
        const int p = ia * 2 + jb;
        float logit = b3v;
        #pragma unroll
        for (int e = 0; e < 8; ++e) {
          const float h2 = fmaxf(acc[p][e] + b2v[e], 0.f);
          logit = fmaf(w3v[e], h2, logit);
        }
        const float score = 1.0f / (1.0f + expf(-logit));
        const int idx = i * 1023 - (i * (i - 1)) / 2 + (j - i - 1);
        out[idx] = score;
        const bool mk = (score > 0.5f) && (stress[i] > smean) && (stress[j] > smean);
        out[P_PAIRS + idx] = mk ? 1.0f : 0.0f;
      }
    }
  }
}

extern "C" void kernel_launch(void* const* d_in, const int* in_sizes, int n_in,
                              void* d_out, int out_size, void* d_ws, size_t ws_size,
                              hipStream_t stream) {
  const float* x     = (const float*)d_in[0];
  const float* ctx   = (const float*)d_in[1];
  const float* W1    = (const float*)d_in[2];
  const float* b1    = (const float*)d_in[3];
  const float* gamma = (const float*)d_in[4];
  const float* beta  = (const float*)d_in[5];
  const float* rmean = (const float*)d_in[6];
  const float* rvar  = (const float*)d_in[7];
  const float* W2    = (const float*)d_in[8];
  const float* b2    = (const float*)d_in[9];
  const float* W3    = (const float*)d_in[10];
  const float* b3    = (const float*)d_in[11];
  float* out = (float*)d_out;

  float* ws     = (float*)d_ws;
  float* pa     = ws;              // 1024*256
  float* pb     = pa + 262144;     // 1024*256
  float* cterm  = pb + 262144;     // 256
  float* w2ft   = cterm + 256;     // 256*8 (transposed [m][e])
  float* b2f    = w2ft + 2048;     // 8
  float* stress = b2f + 8;         // 1024

  hipLaunchKernelGGL(kA, dim3(257), dim3(256), 0, stream, x, ctx, W1, b1, gamma, beta,
                     rmean, rvar, W2, b2, pa, pb, stress, cterm, w2ft, b2f);
  hipLaunchKernelGGL(kC, dim3(64, 64), dim3(64), 0, stream, pa, pb, cterm, w2ft, b2f,
                     W3, b3, stress, out);
}

// Round 4
// 145.731 us; speedup vs baseline: 1.1352x; 1.1352x over previous
//
#include <hip/hip_runtime.h>
#include <math.h>

#define N_NODES 1024
#define F_DIM   128
#define M_DIM   256
#define E_DIM   8
#define P_PAIRS 523776   // N*(N-1)/2

// ---------- Kernel A: pa/pb projections + stress; block 256 does BN-fold/cterm/b2f ----------
__global__ __launch_bounds__(256) void kA(const float* __restrict__ x,
                                          const float* __restrict__ ctx,
                                          const float* __restrict__ W1,
                                          const float* __restrict__ b1,
                                          const float* __restrict__ gamma,
                                          const float* __restrict__ beta,
                                          const float* __restrict__ rmean,
                                          const float* __restrict__ rvar,
                                          const float* __restrict__ W2,
                                          const float* __restrict__ b2,
                                          float* __restrict__ pa,
                                          float* __restrict__ pb,
                                          float* __restrict__ stress,
                                          float* __restrict__ cterm,
                                          float* __restrict__ w2ft,
                                          float* __restrict__ b2f) {
  const int t = threadIdx.x;

  if (blockIdx.x == 256) {
    __shared__ float bnbs[256];
    const float c0 = ctx[0], c1 = ctx[1], c2 = ctx[2], c3 = ctx[3];
    const float* row = W1 + (size_t)t * 260 + 256;
    cterm[t] = b1[t] + c0 * row[0] + c1 * row[1] + c2 * row[2] + c3 * row[3];
    const float s   = gamma[t] / sqrtf(rvar[t] + 1e-5f);
    bnbs[t] = beta[t] - s * rmean[t];
    #pragma unroll
    for (int e = 0; e < 8; ++e) w2ft[t * 8 + e] = W2[e * 256 + t] * s;
    __syncthreads();
    const int wv = t >> 6, lane = t & 63;
    #pragma unroll
    for (int r = 0; r < 2; ++r) {
      const int e = wv * 2 + r;
      float acc = 0.f;
      #pragma unroll
      for (int k = 0; k < 4; ++k) acc += W2[e * 256 + lane + 64 * k] * bnbs[lane + 64 * k];
      #pragma unroll
      for (int m = 32; m > 0; m >>= 1) acc += __shfl_xor(acc, m, 64);
      if (lane == 0) b2f[e] = acc + b2[e];
    }
    return;
  }

  __shared__ float xv[4][128];
  const int n0 = blockIdx.x * 4;
  if (t < 128) {
    ((float4*)&xv[0][0])[t] = ((const float4*)(x + (size_t)n0 * F_DIM))[t];
  }
  __syncthreads();

  {
    const int wv = t >> 6, lane = t & 63;
    const float a = xv[wv][lane], b = xv[wv][lane + 64];
    float sum = a + b;
    #pragma unroll
    for (int m = 32; m > 0; m >>= 1) sum += __shfl_xor(sum, m, 64);
    const float mean = sum * (1.0f / 128.0f);
    const float d0 = a - mean, d1 = b - mean;
    float ss = d0 * d0 + d1 * d1;
    #pragma unroll
    for (int m = 32; m > 0; m >>= 1) ss += __shfl_xor(ss, m, 64);
    if (lane == 0) stress[n0 + wv] = sqrtf(ss * (1.0f / 127.0f));
  }

  const int m = t;
  const float4* wrow = (const float4*)(W1 + (size_t)m * 260);  // W1 row-major [256][260]
  float accA[4] = {0.f, 0.f, 0.f, 0.f};
  float accB[4] = {0.f, 0.f, 0.f, 0.f};
  #pragma unroll 8
  for (int k4 = 0; k4 < 32; ++k4) {
    const float4 wa = wrow[k4];
    const float4 wb = wrow[32 + k4];
    #pragma unroll
    for (int nn = 0; nn < 4; ++nn) {
      const float4 xf = ((const float4*)&xv[nn][0])[k4];
      accA[nn] = fmaf(xf.w, wa.w, fmaf(xf.z, wa.z, fmaf(xf.y, wa.y, fmaf(xf.x, wa.x, accA[nn]))));
      accB[nn] = fmaf(xf.w, wb.w, fmaf(xf.z, wb.z, fmaf(xf.y, wb.y, fmaf(xf.x, wb.x, accB[nn]))));
    }
  }
  #pragma unroll
  for (int nn = 0; nn < 4; ++nn) {
    pa[(size_t)(n0 + nn) * M_DIM + m] = accA[nn];
    pb[(size_t)(n0 + nn) * M_DIM + m] = accB[nn];
  }
}

// ---------- Kernel C: 32x32 pair tiles, 256 threads, m split into two 128-chunks ----------
// LDS = 32 KB (aT 16K + bT 16K) -> 5 blocks/CU = 5 waves/SIMD. Staging writes go to
// LINEAR LDS slots (zero bank conflicts by construction); the rotate-swizzle is applied
// on the global-source column instead (rotation within a contiguous 512B row segment,
// coalescing unaffected). Compute reads are 16-addr/4-lane-broadcast, worst 2-way (free).
__global__ __launch_bounds__(256, 5) void kC(const float* __restrict__ pa,
                                             const float* __restrict__ pb,
                                             const float* __restrict__ cterm,
                                             const float* __restrict__ w2ft,
                                             const float* __restrict__ b2f,
                                             const float* __restrict__ W3,
                                             const float* __restrict__ b3,
                                             const float* __restrict__ stress,
                                             float* __restrict__ out) {
  const int ti = blockIdx.x, tj = blockIdx.y;
  if (tj < ti) return;
  __shared__ float4 a4[32 * 32];   // [row][col4], col4 rotated by row
  __shared__ float4 b4[32 * 32];
  const int t  = threadIdx.x;
  const int i0 = ti * 32, j0 = tj * 32;

  // ---- stressed-node mean (same reduction order as round 3; passed exact) ----
  float ssum = 0.f;
  {
    const int lane = t & 63;
    #pragma unroll
    for (int k = 0; k < 16; ++k) ssum += stress[lane + 64 * k];
    #pragma unroll
    for (int m = 32; m > 0; m >>= 1) ssum += __shfl_xor(ssum, m, 64);
  }
  const float smean = ssum * (1.0f / 1024.0f);

  const int jx = t & 15;   // j within tile
  const int iy = t >> 4;   // i within tile
  float acc[4][8];         // [pair 00,01,10,11][e]
  #pragma unroll
  for (int p = 0; p < 4; ++p)
    #pragma unroll
    for (int e = 0; e < 8; ++e) acc[p][e] = 0.f;

  const float4* pa4 = (const float4*)pa;
  const float4* pb4 = (const float4*)pb;
  const float4* ct4 = (const float4*)cterm;
  const float4* w4g = (const float4*)w2ft;

  for (int cb = 0; cb < 2; ++cb) {
    if (cb) __syncthreads();
    // ---- stage chunk cb: linear LDS writes, rotated global source column ----
    #pragma unroll
    for (int p = 0; p < 4; ++p) {
      const int d  = p * 256 + t;      // float4 slot 0..1023
      const int r  = d >> 5;           // row 0..31
      const int dc = d & 31;           // dest col4
      const int c  = (dc - r) & 31;    // source col4 within chunk
      const float4 cv = ct4[cb * 32 + c];
      float4 av = pa4[(size_t)(i0 + r) * 64 + cb * 32 + c];
      av.x += cv.x; av.y += cv.y; av.z += cv.z; av.w += cv.w;
      a4[d] = av;
      b4[d] = pb4[(size_t)(j0 + r) * 64 + cb * 32 + c];
    }
    __syncthreads();

    // ---- compute chunk cb ----
    #pragma unroll 2
    for (int m4 = 0; m4 < 32; ++m4) {
      const float4 a0 = a4[iy * 32        + ((m4 + iy) & 31)];
      const float4 a1 = a4[(iy + 16) * 32 + ((m4 + iy + 16) & 31)];
      const float4 b0 = b4[jx * 32        + ((m4 + jx) & 31)];
      const float4 b1 = b4[(jx + 16) * 32 + ((m4 + jx + 16) & 31)];
      float4 w[8];
      #pragma unroll
      for (int q = 0; q < 8; ++q) w[q] = w4g[(cb * 32 + m4) * 8 + q];  // uniform -> s_load

      const float* a0f = (const float*)&a0;
      const float* a1f = (const float*)&a1;
      const float* b0f = (const float*)&b0;
      const float* b1f = (const float*)&b1;
      #pragma unroll
      for (int mm = 0; mm < 4; ++mm) {
        const float r00 = fmaxf(a0f[mm] + b0f[mm], 0.f);
        const float r01 = fmaxf(a0f[mm] + b1f[mm], 0.f);
        const float r10 = fmaxf(a1f[mm] + b0f[mm], 0.f);
        const float r11 = fmaxf(a1f[mm] + b1f[mm], 0.f);
        const float* wl = (const float*)&w[mm * 2];      // e 0..3
        const float* wh = (const float*)&w[mm * 2 + 1];  // e 4..7
        #pragma unroll
        for (int e = 0; e < 4; ++e) {
          acc[0][e]     = fmaf(wl[e], r00, acc[0][e]);
          acc[1][e]     = fmaf(wl[e], r01, acc[1][e]);
          acc[2][e]     = fmaf(wl[e], r10, acc[2][e]);
          acc[3][e]     = fmaf(wl[e], r11, acc[3][e]);
          acc[0][e + 4] = fmaf(wh[e], r00, acc[0][e + 4]);
          acc[1][e + 4] = fmaf(wh[e], r01, acc[1][e + 4]);
          acc[2][e + 4] = fmaf(wh[e], r10, acc[2][e + 4]);
          acc[3][e + 4] = fmaf(wh[e], r11, acc[3][e + 4]);
        }
      }
    }
  }

  // ---- epilogue: second relu, W3 dot, sigmoid, mask, triu store ----
  float w3v[8], b2v[8];
  #pragma unroll
  for (int e = 0; e < 8; ++e) { w3v[e] = W3[e]; b2v[e] = b2f[e]; }
  const float b3v = b3[0];
  #pragma unroll
  for (int ia = 0; ia < 2; ++ia) {
    #pragma unroll
    for (int jb = 0; jb < 2; ++jb) {
      const int i = i0 + iy + ia * 16;
      const int j = j0 + jx + jb * 16;
      if (i < j) {
        const int p = ia * 2 + jb;
        float logit = b3v;
        #pragma unroll
        for (int e = 0; e < 8; ++e) {
          const float h2 = fmaxf(acc[p][e] + b2v[e], 0.f);
          logit = fmaf(w3v[e], h2, logit);
        }
        const float score = 1.0f / (1.0f + expf(-logit));
        const int idx = i * 1023 - (i * (i - 1)) / 2 + (j - i - 1);
        out[idx] = score;
        const bool mk = (score > 0.5f) && (stress[i] > smean) && (stress[j] > smean);
        out[P_PAIRS + idx] = mk ? 1.0f : 0.0f;
      }
    }
  }
}

extern "C" void kernel_launch(void* const* d_in, const int* in_sizes, int n_in,
                              void* d_out, int out_size, void* d_ws, size_t ws_size,
                              hipStream_t stream) {
  const float* x     = (const float*)d_in[0];
  const float* ctx   = (const float*)d_in[1];
  const float* W1    = (const float*)d_in[2];
  const float* b1    = (const float*)d_in[3];
  const float* gamma = (const float*)d_in[4];
  const float* beta  = (const float*)d_in[5];
  const float* rmean = (const float*)d_in[6];
  const float* rvar  = (const float*)d_in[7];
  const float* W2    = (const float*)d_in[8];
  const float* b2    = (const float*)d_in[9];
  const float* W3    = (const float*)d_in[10];
  const float* b3    = (const float*)d_in[11];
  float* out = (float*)d_out;

  float* ws     = (float*)d_ws;
  float* pa     = ws;              // 1024*256
  float* pb     = pa + 262144;     // 1024*256
  float* cterm  = pb + 262144;     // 256
  float* w2ft   = cterm + 256;     // 256*8 (transposed [m][e])
  float* b2f    = w2ft + 2048;     // 8
  float* stress = b2f + 8;         // 1024

  hipLaunchKernelGGL(kA, dim3(257), dim3(256), 0, stream, x, ctx, W1, b1, gamma, beta,
                     rmean, rvar, W2, b2, pa, pb, stress, cterm, w2ft, b2f);
  hipLaunchKernelGGL(kC, dim3(32, 32), dim3(256), 0, stream, pa, pb, cterm, w2ft, b2f,
                     W3, b3, stress, out);
}

// Round 5
// 135.922 us; speedup vs baseline: 1.2172x; 1.0722x over previous
//
#include <hip/hip_runtime.h>
#include <math.h>

#define N_NODES 1024
#define F_DIM   128
#define M_DIM   256
#define E_DIM   8
#define P_PAIRS 523776   // N*(N-1)/2
#define NTILES  528      // 32*33/2 triangular 32x32 tiles

// ---------- Kernel A: pa/pb projections (+cterm folded into pa) + stress;
// ---------- block 256 does BN-fold/b2f/w2ft ----------
__global__ __launch_bounds__(256) void kA(const float* __restrict__ x,
                                          const float* __restrict__ ctx,
                                          const float* __restrict__ W1,
                                          const float* __restrict__ b1,
                                          const float* __restrict__ gamma,
                                          const float* __restrict__ beta,
                                          const float* __restrict__ rmean,
                                          const float* __restrict__ rvar,
                                          const float* __restrict__ W2,
                                          const float* __restrict__ b2,
                                          float* __restrict__ pa,
                                          float* __restrict__ pb,
                                          float* __restrict__ stress,
                                          float* __restrict__ w2ft,
                                          float* __restrict__ b2f) {
  const int t = threadIdx.x;

  if (blockIdx.x == 256) {
    __shared__ float bnbs[256];
    const float s   = gamma[t] / sqrtf(rvar[t] + 1e-5f);
    bnbs[t] = beta[t] - s * rmean[t];
    #pragma unroll
    for (int e = 0; e < 8; ++e) w2ft[t * 8 + e] = W2[e * 256 + t] * s;
    __syncthreads();
    const int wv = t >> 6, lane = t & 63;
    #pragma unroll
    for (int r = 0; r < 2; ++r) {
      const int e = wv * 2 + r;
      float acc = 0.f;
      #pragma unroll
      for (int k = 0; k < 4; ++k) acc += W2[e * 256 + lane + 64 * k] * bnbs[lane + 64 * k];
      #pragma unroll
      for (int m = 32; m > 0; m >>= 1) acc += __shfl_xor(acc, m, 64);
      if (lane == 0) b2f[e] = acc + b2[e];
    }
    return;
  }

  __shared__ float xv[4][128];
  const int n0 = blockIdx.x * 4;
  if (t < 128) {
    ((float4*)&xv[0][0])[t] = ((const float4*)(x + (size_t)n0 * F_DIM))[t];
  }
  __syncthreads();

  {
    const int wv = t >> 6, lane = t & 63;
    const float a = xv[wv][lane], b = xv[wv][lane + 64];
    float sum = a + b;
    #pragma unroll
    for (int m = 32; m > 0; m >>= 1) sum += __shfl_xor(sum, m, 64);
    const float mean = sum * (1.0f / 128.0f);
    const float d0 = a - mean, d1 = b - mean;
    float ss = d0 * d0 + d1 * d1;
    #pragma unroll
    for (int m = 32; m > 0; m >>= 1) ss += __shfl_xor(ss, m, 64);
    if (lane == 0) stress[n0 + wv] = sqrtf(ss * (1.0f / 127.0f));
  }

  const int m = t;
  const float4* wrow = (const float4*)(W1 + (size_t)m * 260);  // W1 row-major [256][260]
  float accA[4] = {0.f, 0.f, 0.f, 0.f};
  float accB[4] = {0.f, 0.f, 0.f, 0.f};
  #pragma unroll 8
  for (int k4 = 0; k4 < 32; ++k4) {
    const float4 wa = wrow[k4];
    const float4 wb = wrow[32 + k4];
    #pragma unroll
    for (int nn = 0; nn < 4; ++nn) {
      const float4 xf = ((const float4*)&xv[nn][0])[k4];
      accA[nn] = fmaf(xf.w, wa.w, fmaf(xf.z, wa.z, fmaf(xf.y, wa.y, fmaf(xf.x, wa.x, accA[nn]))));
      accB[nn] = fmaf(xf.w, wb.w, fmaf(xf.z, wb.z, fmaf(xf.y, wb.y, fmaf(xf.x, wb.x, accB[nn]))));
    }
  }
  // cterm for this m, computed redundantly per block (W1 tail + b1 are L2-hot)
  const float c0 = ctx[0], c1 = ctx[1], c2 = ctx[2], c3 = ctx[3];
  const float* rowt = W1 + (size_t)m * 260 + 256;
  const float ctv = b1[m] + c0 * rowt[0] + c1 * rowt[1] + c2 * rowt[2] + c3 * rowt[3];
  #pragma unroll
  for (int nn = 0; nn < 4; ++nn) {
    pa[(size_t)(n0 + nn) * M_DIM + m] = accA[nn] + ctv;   // cterm folded (bit-exact)
    pb[(size_t)(n0 + nn) * M_DIM + m] = accB[nn];
  }
}

// ---------- Kernel C: 528 triangular 32x32 tiles, 256 threads, reg-dbuf staging ----------
// LDS 32 KB. Staging writes linear (zero conflicts); rotate-swizzle on the global
// source column. Compute reads worst 2-way (free). w2ft wave-uniform -> s_load.
__global__ __launch_bounds__(256, 4) void kC(const float* __restrict__ pa,
                                             const float* __restrict__ pb,
                                             const float* __restrict__ w2ft,
                                             const float* __restrict__ b2f,
                                             const float* __restrict__ W3,
                                             const float* __restrict__ b3,
                                             const float* __restrict__ stress,
                                             float* __restrict__ out) {
  __shared__ float4 a4[32 * 32];   // [row][col4], col4 rotated by row
  __shared__ float4 b4[32 * 32];
  const int t = threadIdx.x;

  // triangular decode: p = tj*(tj+1)/2 + ti, ti<=tj
  const int p = blockIdx.x;
  int tj = (int)((sqrtf(8.0f * (float)p + 1.0f) - 1.0f) * 0.5f);
  while ((tj + 1) * (tj + 2) / 2 <= p) ++tj;
  while (tj * (tj + 1) / 2 > p) --tj;
  const int ti = p - tj * (tj + 1) / 2;
  const int i0 = ti * 32, j0 = tj * 32;

  // stressed-node mean (same reduction order as rounds 3-4)
  float ssum = 0.f;
  {
    const int lane = t & 63;
    #pragma unroll
    for (int k = 0; k < 16; ++k) ssum += stress[lane + 64 * k];
    #pragma unroll
    for (int m = 32; m > 0; m >>= 1) ssum += __shfl_xor(ssum, m, 64);
  }
  const float smean = ssum * (1.0f / 1024.0f);

  const int jx = t & 15;   // j within tile
  const int iy = t >> 4;   // i within tile
  float acc[4][8];         // [pair 00,01,10,11][e]
  #pragma unroll
  for (int q = 0; q < 4; ++q)
    #pragma unroll
    for (int e = 0; e < 8; ++e) acc[q][e] = 0.f;

  const float4* pa4 = (const float4*)pa;
  const float4* pb4 = (const float4*)pb;
  const float4* w4g = (const float4*)w2ft;

  float4 ra[4], rb[4];

  // ---- stage chunk 0 ----
  #pragma unroll
  for (int q = 0; q < 4; ++q) {
    const int d = q * 256 + t, r = d >> 5, dc = d & 31, c = (dc - r) & 31;
    ra[q] = pa4[(size_t)(i0 + r) * 64 + c];
    rb[q] = pb4[(size_t)(j0 + r) * 64 + c];
  }
  #pragma unroll
  for (int q = 0; q < 4; ++q) {
    const int d = q * 256 + t;
    a4[d] = ra[q];
    b4[d] = rb[q];
  }
  __syncthreads();

  // ---- prefetch chunk 1 into registers (in flight during chunk-0 compute) ----
  #pragma unroll
  for (int q = 0; q < 4; ++q) {
    const int d = q * 256 + t, r = d >> 5, dc = d & 31, c = (dc - r) & 31;
    ra[q] = pa4[(size_t)(i0 + r) * 64 + 32 + c];
    rb[q] = pb4[(size_t)(j0 + r) * 64 + 32 + c];
  }

  auto computeChunk = [&](int cw) {
    #pragma unroll 4
    for (int m4 = 0; m4 < 32; ++m4) {
      const float4 a0 = a4[iy * 32        + ((m4 + iy) & 31)];
      const float4 a1 = a4[(iy + 16) * 32 + ((m4 + iy + 16) & 31)];
      const float4 b0 = b4[jx * 32        + ((m4 + jx) & 31)];
      const float4 b1 = b4[(jx + 16) * 32 + ((m4 + jx + 16) & 31)];
      float4 w[8];
      #pragma unroll
      for (int q = 0; q < 8; ++q) w[q] = w4g[(cw + m4) * 8 + q];  // uniform -> s_load

      const float* a0f = (const float*)&a0;
      const float* a1f = (const float*)&a1;
      const float* b0f = (const float*)&b0;
      const float* b1f = (const float*)&b1;
      #pragma unroll
      for (int mm = 0; mm < 4; ++mm) {
        const float r00 = fmaxf(a0f[mm] + b0f[mm], 0.f);
        const float r01 = fmaxf(a0f[mm] + b1f[mm], 0.f);
        const float r10 = fmaxf(a1f[mm] + b0f[mm], 0.f);
        const float r11 = fmaxf(a1f[mm] + b1f[mm], 0.f);
        const float* wl = (const float*)&w[mm * 2];      // e 0..3
        const float* wh = (const float*)&w[mm * 2 + 1];  // e 4..7
        #pragma unroll
        for (int e = 0; e < 4; ++e) {
          acc[0][e]     = fmaf(wl[e], r00, acc[0][e]);
          acc[1][e]     = fmaf(wl[e], r01, acc[1][e]);
          acc[2][e]     = fmaf(wl[e], r10, acc[2][e]);
          acc[3][e]     = fmaf(wl[e], r11, acc[3][e]);
          acc[0][e + 4] = fmaf(wh[e], r00, acc[0][e + 4]);
          acc[1][e + 4] = fmaf(wh[e], r01, acc[1][e + 4]);
          acc[2][e + 4] = fmaf(wh[e], r10, acc[2][e + 4]);
          acc[3][e + 4] = fmaf(wh[e], r11, acc[3][e + 4]);
        }
      }
    }
  };

  computeChunk(0);
  __syncthreads();
  #pragma unroll
  for (int q = 0; q < 4; ++q) {
    const int d = q * 256 + t;
    a4[d] = ra[q];
    b4[d] = rb[q];
  }
  __syncthreads();
  computeChunk(32);

  // ---- epilogue: second relu, W3 dot, sigmoid, mask, triu store ----
  float w3v[8], b2v[8];
  #pragma unroll
  for (int e = 0; e < 8; ++e) { w3v[e] = W3[e]; b2v[e] = b2f[e]; }
  const float b3v = b3[0];
  #pragma unroll
  for (int ia = 0; ia < 2; ++ia) {
    #pragma unroll
    for (int jb = 0; jb < 2; ++jb) {
      const int i = i0 + iy + ia * 16;
      const int j = j0 + jx + jb * 16;
      if (i < j) {
        const int q = ia * 2 + jb;
        float logit = b3v;
        #pragma unroll
        for (int e = 0; e < 8; ++e) {
          const float h2 = fmaxf(acc[q][e] + b2v[e], 0.f);
          logit = fmaf(w3v[e], h2, logit);
        }
        const float score = 1.0f / (1.0f + expf(-logit));
        const int idx = i * 1023 - (i * (i - 1)) / 2 + (j - i - 1);
        out[idx] = score;
        const bool mk = (score > 0.5f) && (stress[i] > smean) && (stress[j] > smean);
        out[P_PAIRS + idx] = mk ? 1.0f : 0.0f;
      }
    }
  }
}

extern "C" void kernel_launch(void* const* d_in, const int* in_sizes, int n_in,
                              void* d_out, int out_size, void* d_ws, size_t ws_size,
                              hipStream_t stream) {
  const float* x     = (const float*)d_in[0];
  const float* ctx   = (const float*)d_in[1];
  const float* W1    = (const float*)d_in[2];
  const float* b1    = (const float*)d_in[3];
  const float* gamma = (const float*)d_in[4];
  const float* beta  = (const float*)d_in[5];
  const float* rmean = (const float*)d_in[6];
  const float* rvar  = (const float*)d_in[7];
  const float* W2    = (const float*)d_in[8];
  const float* b2    = (const float*)d_in[9];
  const float* W3    = (const float*)d_in[10];
  const float* b3    = (const float*)d_in[11];
  float* out = (float*)d_out;

  float* ws     = (float*)d_ws;
  float* pa     = ws;              // 1024*256 (cterm pre-folded)
  float* pb     = pa + 262144;     // 1024*256
  float* w2ft   = pb + 262144;     // 256*8 (transposed [m][e], BN-scaled)
  float* b2f    = w2ft + 2048;     // 8
  float* stress = b2f + 8;         // 1024

  hipLaunchKernelGGL(kA, dim3(257), dim3(256), 0, stream, x, ctx, W1, b1, gamma, beta,
                     rmean, rvar, W2, b2, pa, pb, stress, w2ft, b2f);
  hipLaunchKernelGGL(kC, dim3(NTILES), dim3(256), 0, stream, pa, pb, w2ft, b2f,
                     W3, b3, stress, out);
}

// Round 6
// 129.852 us; speedup vs baseline: 1.2741x; 1.0467x over previous
//
#include <hip/hip_runtime.h>
#include <math.h>

#define N_NODES 1024
#define F_DIM   128
#define M_DIM   256
#define E_DIM   8
#define P_PAIRS 523776   // N*(N-1)/2
#define NBLK    1056     // sum_{tj=0..31} (2*tj+2) 16x32 tiles

// ---------- Kernel A: pa/pb projections (+cterm folded into pa) + stress;
// ---------- block 256 does BN-fold/b2f/w2ft ----------
__global__ __launch_bounds__(256) void kA(const float* __restrict__ x,
                                          const float* __restrict__ ctx,
                                          const float* __restrict__ W1,
                                          const float* __restrict__ b1,
                                          const float* __restrict__ gamma,
                                          const float* __restrict__ beta,
                                          const float* __restrict__ rmean,
                                          const float* __restrict__ rvar,
                                          const float* __restrict__ W2,
                                          const float* __restrict__ b2,
                                          float* __restrict__ pa,
                                          float* __restrict__ pb,
                                          float* __restrict__ stress,
                                          float* __restrict__ w2ft,
                                          float* __restrict__ b2f) {
  const int t = threadIdx.x;

  if (blockIdx.x == 256) {
    __shared__ float bnbs[256];
    const float s   = gamma[t] / sqrtf(rvar[t] + 1e-5f);
    bnbs[t] = beta[t] - s * rmean[t];
    #pragma unroll
    for (int e = 0; e < 8; ++e) w2ft[t * 8 + e] = W2[e * 256 + t] * s;
    __syncthreads();
    const int wv = t >> 6, lane = t & 63;
    #pragma unroll
    for (int r = 0; r < 2; ++r) {
      const int e = wv * 2 + r;
      float acc = 0.f;
      #pragma unroll
      for (int k = 0; k < 4; ++k) acc += W2[e * 256 + lane + 64 * k] * bnbs[lane + 64 * k];
      #pragma unroll
      for (int m = 32; m > 0; m >>= 1) acc += __shfl_xor(acc, m, 64);
      if (lane == 0) b2f[e] = acc + b2[e];
    }
    return;
  }

  __shared__ float xv[4][128];
  const int n0 = blockIdx.x * 4;
  if (t < 128) {
    ((float4*)&xv[0][0])[t] = ((const float4*)(x + (size_t)n0 * F_DIM))[t];
  }
  __syncthreads();

  {
    const int wv = t >> 6, lane = t & 63;
    const float a = xv[wv][lane], b = xv[wv][lane + 64];
    float sum = a + b;
    #pragma unroll
    for (int m = 32; m > 0; m >>= 1) sum += __shfl_xor(sum, m, 64);
    const float mean = sum * (1.0f / 128.0f);
    const float d0 = a - mean, d1 = b - mean;
    float ss = d0 * d0 + d1 * d1;
    #pragma unroll
    for (int m = 32; m > 0; m >>= 1) ss += __shfl_xor(ss, m, 64);
    if (lane == 0) stress[n0 + wv] = sqrtf(ss * (1.0f / 127.0f));
  }

  const int m = t;
  const float4* wrow = (const float4*)(W1 + (size_t)m * 260);  // W1 row-major [256][260]
  float accA[4] = {0.f, 0.f, 0.f, 0.f};
  float accB[4] = {0.f, 0.f, 0.f, 0.f};
  #pragma unroll 8
  for (int k4 = 0; k4 < 32; ++k4) {
    const float4 wa = wrow[k4];
    const float4 wb = wrow[32 + k4];
    #pragma unroll
    for (int nn = 0; nn < 4; ++nn) {
      const float4 xf = ((const float4*)&xv[nn][0])[k4];
      accA[nn] = fmaf(xf.w, wa.w, fmaf(xf.z, wa.z, fmaf(xf.y, wa.y, fmaf(xf.x, wa.x, accA[nn]))));
      accB[nn] = fmaf(xf.w, wb.w, fmaf(xf.z, wb.z, fmaf(xf.y, wb.y, fmaf(xf.x, wb.x, accB[nn]))));
    }
  }
  const float c0 = ctx[0], c1 = ctx[1], c2 = ctx[2], c3 = ctx[3];
  const float* rowt = W1 + (size_t)m * 260 + 256;
  const float ctv = b1[m] + c0 * rowt[0] + c1 * rowt[1] + c2 * rowt[2] + c3 * rowt[3];
  #pragma unroll
  for (int nn = 0; nn < 4; ++nn) {
    pa[(size_t)(n0 + nn) * M_DIM + m] = accA[nn] + ctv;   // cterm folded (bit-exact)
    pb[(size_t)(n0 + nn) * M_DIM + m] = accB[nn];
  }
}

// ---------- Kernel C: 1056 triangular 16x32 tiles, 256 threads, 2 pairs/thread ----------
// w2ft read per-m4 via wave-uniform GLOBAL loads (vmcnt) software-pipelined one
// iteration ahead; tile reads via ds_read_b128 (lgkm, in-order) -> the two latency
// domains decouple. Staging writes linear LDS (zero conflicts); rotate-swizzle on the
// global source column; compute reads are broadcast-heavy, worst 2-way (free).
__global__ __launch_bounds__(256, 4) void kC(const float* __restrict__ pa,
                                             const float* __restrict__ pb,
                                             const float* __restrict__ w2ft,
                                             const float* __restrict__ b2f,
                                             const float* __restrict__ W3,
                                             const float* __restrict__ b3,
                                             const float* __restrict__ stress,
                                             float* __restrict__ out) {
  __shared__ float4 a4[16 * 32];   // 16 i-rows x 32 float4 (128 m chunk), col rotated
  __shared__ float4 b4[32 * 32];   // 32 j-rows
  const int t = threadIdx.x;

  // decode p -> (tj, si): p = tj*(tj+1) + si, si in [0, 2*tj+2)
  const int p = blockIdx.x;
  int tj = (int)((sqrtf(4.0f * (float)p + 1.0f) - 1.0f) * 0.5f);
  while ((tj + 1) * (tj + 2) <= p) ++tj;
  while (tj * (tj + 1) > p) --tj;
  const int si = p - tj * (tj + 1);
  const int i0 = si * 16, j0 = tj * 32;

  // stressed-node mean (same reduction order as rounds 3-5)
  float ssum = 0.f;
  {
    const int lane = t & 63;
    #pragma unroll
    for (int k = 0; k < 16; ++k) ssum += stress[lane + 64 * k];
    #pragma unroll
    for (int m = 32; m > 0; m >>= 1) ssum += __shfl_xor(ssum, m, 64);
  }
  const float smean = ssum * (1.0f / 1024.0f);

  const int jx = t & 15;   // j within tile (pairs at jx and jx+16)
  const int iy = t >> 4;   // i within tile, 0..15
  float acc[2][8];
  #pragma unroll
  for (int q = 0; q < 2; ++q)
    #pragma unroll
    for (int e = 0; e < 8; ++e) acc[q][e] = 0.f;

  const float4* pa4 = (const float4*)pa;
  const float4* pb4 = (const float4*)pb;
  const float4* w4g = (const float4*)w2ft;

  float4 rg[6];

  // ---- stage chunk 0 (slots: 0..511 = a, 512..1535 = b) ----
  #pragma unroll
  for (int q = 0; q < 6; ++q) {
    const int d = q * 256 + t;
    if (q < 2) {
      const int r = d >> 5, dc = d & 31, c = (dc - r) & 31;
      rg[q] = pa4[(size_t)(i0 + r) * 64 + c];
    } else {
      const int d2 = d - 512, r = d2 >> 5, dc = d2 & 31, c = (dc - r) & 31;
      rg[q] = pb4[(size_t)(j0 + r) * 64 + c];
    }
  }
  #pragma unroll
  for (int q = 0; q < 6; ++q) {
    const int d = q * 256 + t;
    if (q < 2) a4[d] = rg[q]; else b4[d - 512] = rg[q];
  }
  __syncthreads();

  // ---- prefetch chunk 1 into registers ----
  #pragma unroll
  for (int q = 0; q < 6; ++q) {
    const int d = q * 256 + t;
    if (q < 2) {
      const int r = d >> 5, dc = d & 31, c = (dc - r) & 31;
      rg[q] = pa4[(size_t)(i0 + r) * 64 + 32 + c];
    } else {
      const int d2 = d - 512, r = d2 >> 5, dc = d2 & 31, c = (dc - r) & 31;
      rg[q] = pb4[(size_t)(j0 + r) * 64 + 32 + c];
    }
  }

  auto computeChunk = [&](int cw) {
    float4 wc[8], wn[8];
    #pragma unroll
    for (int q = 0; q < 8; ++q) wc[q] = w4g[cw * 8 + q];
    for (int m4 = 0; m4 < 32; ++m4) {
      // prefetch next iteration's w (vmcnt domain; hidden behind FMAs)
      if (m4 < 31) {
        #pragma unroll
        for (int q = 0; q < 8; ++q) wn[q] = w4g[(cw + m4 + 1) * 8 + q];
      }
      const float4 a0 = a4[iy * 32        + ((m4 + iy) & 31)];
      const float4 b0 = b4[jx * 32        + ((m4 + jx) & 31)];
      const float4 b1 = b4[(jx + 16) * 32 + ((m4 + jx + 16) & 31)];
      const float* a0f = (const float*)&a0;
      const float* b0f = (const float*)&b0;
      const float* b1f = (const float*)&b1;
      #pragma unroll
      for (int mm = 0; mm < 4; ++mm) {
        const float r0 = fmaxf(a0f[mm] + b0f[mm], 0.f);
        const float r1 = fmaxf(a0f[mm] + b1f[mm], 0.f);
        const float* wl = (const float*)&wc[mm * 2];      // e 0..3
        const float* wh = (const float*)&wc[mm * 2 + 1];  // e 4..7
        #pragma unroll
        for (int e = 0; e < 4; ++e) {
          acc[0][e]     = fmaf(wl[e], r0, acc[0][e]);
          acc[1][e]     = fmaf(wl[e], r1, acc[1][e]);
          acc[0][e + 4] = fmaf(wh[e], r0, acc[0][e + 4]);
          acc[1][e + 4] = fmaf(wh[e], r1, acc[1][e + 4]);
        }
      }
      #pragma unroll
      for (int q = 0; q < 8; ++q) wc[q] = wn[q];
    }
  };

  computeChunk(0);
  __syncthreads();
  #pragma unroll
  for (int q = 0; q < 6; ++q) {
    const int d = q * 256 + t;
    if (q < 2) a4[d] = rg[q]; else b4[d - 512] = rg[q];
  }
  __syncthreads();
  computeChunk(32);

  // ---- epilogue ----
  float w3v[8], b2v[8];
  #pragma unroll
  for (int e = 0; e < 8; ++e) { w3v[e] = W3[e]; b2v[e] = b2f[e]; }
  const float b3v = b3[0];
  const int i = i0 + iy;
  #pragma unroll
  for (int jb = 0; jb < 2; ++jb) {
    const int j = j0 + jx + jb * 16;
    if (i < j) {
      float logit = b3v;
      #pragma unroll
      for (int e = 0; e < 8; ++e) {
        const float h2 = fmaxf(acc[jb][e] + b2v[e], 0.f);
        logit = fmaf(w3v[e], h2, logit);
      }
      const float score = 1.0f / (1.0f + expf(-logit));
      const int idx = i * 1023 - (i * (i - 1)) / 2 + (j - i - 1);
      out[idx] = score;
      const bool mk = (score > 0.5f) && (stress[i] > smean) && (stress[j] > smean);
      out[P_PAIRS + idx] = mk ? 1.0f : 0.0f;
    }
  }
}

extern "C" void kernel_launch(void* const* d_in, const int* in_sizes, int n_in,
                              void* d_out, int out_size, void* d_ws, size_t ws_size,
                              hipStream_t stream) {
  const float* x     = (const float*)d_in[0];
  const float* ctx   = (const float*)d_in[1];
  const float* W1    = (const float*)d_in[2];
  const float* b1    = (const float*)d_in[3];
  const float* gamma = (const float*)d_in[4];
  const float* beta  = (const float*)d_in[5];
  const float* rmean = (const float*)d_in[6];
  const float* rvar  = (const float*)d_in[7];
  const float* W2    = (const float*)d_in[8];
  const float* b2    = (const float*)d_in[9];
  const float* W3    = (const float*)d_in[10];
  const float* b3    = (const float*)d_in[11];
  float* out = (float*)d_out;

  float* ws     = (float*)d_ws;
  float* pa     = ws;              // 1024*256 (cterm pre-folded)
  float* pb     = pa + 262144;     // 1024*256
  float* w2ft   = pb + 262144;     // 256*8 (transposed [m][e], BN-scaled)
  float* b2f    = w2ft + 2048;     // 8
  float* stress = b2f + 8;         // 1024

  hipLaunchKernelGGL(kA, dim3(257), dim3(256), 0, stream, x, ctx, W1, b1, gamma, beta,
                     rmean, rvar, W2, b2, pa, pb, stress, w2ft, b2f);
  hipLaunchKernelGGL(kC, dim3(NBLK), dim3(256), 0, stream, pa, pb, w2ft, b2f,
                     W3, b3, stress, out);
}